// Round 3
// baseline (291.612 us; speedup 1.0000x reference)
//
#include <hip/hip_runtime.h>

#define NPG 100     // nodes per graph
#define HF 64       // hidden width
#define NROW 128    // node rows padded to 4 x 32 tiles
#define SA 120      // Arm row stride (bf16): 112 k-slots + 8 pad (240 B, 16B-aligned)
#define ST 72       // Trm row stride (bf16): 64 + 8 pad (144 B, 16B-aligned)

typedef float  f4   __attribute__((ext_vector_type(4)));
typedef float  f16v __attribute__((ext_vector_type(16)));
typedef short  bf8  __attribute__((ext_vector_type(8)));

#define SZ_ARM (NROW * SA * 2)        // 30720
#define SZ_TRM (NROW * ST * 2)        // 18432
#define OFF_ARM 0
#define OFF_P   SZ_ARM                // 30720
#define OFF_Q   (OFF_P + SZ_TRM)      // 49152 (ends 67584)
#define OFF_AF  OFF_P                 // fp32 A staging 100x100 = 40000 B overlay (ends 70720)
#define OFF_MISC 70720
#define SMEM_BYTES (OFF_MISC + 1792)  // 72512 -> 2 blocks/CU (145 KB < 160 KB)

__device__ __forceinline__ unsigned short f2bf(float f) {
    unsigned u = __float_as_uint(f);
    u += 0x7fffu + ((u >> 16) & 1u);   // round-to-nearest-even
    return (unsigned short)(u >> 16);
}
__device__ __forceinline__ float bf2f(unsigned short h) {
    return __uint_as_float(((unsigned)h) << 16);
}
__device__ __forceinline__ f16v zerov16() {
    f16v z;
    #pragma unroll
    for (int i = 0; i < 16; i++) z[i] = 0.f;
    return z;
}

// One block per graph, 256 threads = 4 waves, 2 blocks/CU.
// All matmuls on mfma_f32_32x32x16_bf16.
//   LHAT: D[n_out][f] = sum_k Arm[n_out][k] * Trm[k][f]   (A=Arm b128, B=Trm strided b16)
//   TW:   O[n][fo]   += sum_fi Trm[n][fi] * W[fi][fo]      (A=Trm b128, B=W from global)
// C/D: col = lane&31, row = (reg&3)+8*(reg>>2)+4*(lane>>5)  [verified layout]
// Wave wg owns f-tile Ntf=wg&1 (cols Ntf*32..+31) and node-tiles {2*(wg>>1), 2*(wg>>1)+1}.
// Chebyshev old term (Tx_{s-2}) kept in fp32 registers (fixed lane ownership).
__launch_bounds__(256, 2)
__global__ void cheb32(const float* __restrict__ x, const int* __restrict__ ei,
                       const float* __restrict__ lambda_max,
                       const float* __restrict__ W1, const float* __restrict__ b1,
                       const float* __restrict__ W2, const float* __restrict__ b2,
                       const float* __restrict__ W3, const float* __restrict__ b3,
                       const float* __restrict__ bng, const float* __restrict__ bnb,
                       const float* __restrict__ bnm, const float* __restrict__ bnv,
                       const float* __restrict__ fc1w, const float* __restrict__ fc1b,
                       const float* __restrict__ fc2w, const float* __restrict__ fc2b,
                       float* __restrict__ out, int E_total, int epg)
{
    extern __shared__ char sm[];
    const int tid = threadIdx.x;
    const int g = blockIdx.x;
    const int ebase = g * epg, nbase = g * NPG;
    const int wg = tid >> 6, lane = tid & 63;
    const int l31 = lane & 31, hh = lane >> 5;
    const int Ntf = wg & 1;
    const int Mt0 = (wg >> 1) * 2;
    const int fo = Ntf * 32 + l31;

    float* Af     = (float*)(sm + OFF_AF);
    int*   deg    = (int*)(sm + OFF_MISC);
    float* dis    = (float*)(sm + OFF_MISC + 512);
    float* pool   = (float*)(sm + OFF_MISC + 1024);
    float* gvn    = (float*)(sm + OFF_MISC + 1280);
    float* zf     = (float*)(sm + OFF_MISC + 1536);
    float* logits = (float*)(sm + OFF_MISC + 1664);
    float* lsep   = (float*)(sm + OFF_MISC + 1728);

    const float lam = lambda_max[g];
    const float two_l = 2.0f / lam;
    const float cl = two_l - 1.0f;

    // ---------------- build dense Lhat (fp32 staging -> bf16 Arm) ----------------
    for (int i = tid; i < 2500; i += 256) ((f4*)Af)[i] = (f4){0.f, 0.f, 0.f, 0.f};
    if (tid < NPG) deg[tid] = 0;
    if (tid < HF) pool[tid] = 0.f;
    __syncthreads();
    for (int e = tid; e < epg; e += 256)
        atomicAdd(&deg[ei[ebase + e] - nbase], 1);
    __syncthreads();
    if (tid < NPG) dis[tid] = deg[tid] > 0 ? rsqrtf((float)deg[tid]) : 0.f;
    __syncthreads();
    for (int e = tid; e < epg; e += 256) {
        int r = ei[ebase + e] - nbase;
        int c = ei[E_total + ebase + e] - nbase;
        atomicAdd(&Af[r * NPG + c], -two_l * dis[r] * dis[c]);
    }
    __syncthreads();
    if (tid < NPG) Af[tid * NPG + tid] += cl;
    __syncthreads();
    // Arm[128][120]: data cols 0..111, zero outside 100x100
    for (int u = tid; u < NROW * 56; u += 256) {
        int n = u / 56, p = (u % 56) * 2;
        float v0 = (n < NPG && p     < NPG) ? Af[n * NPG + p]     : 0.f;
        float v1 = (n < NPG && p + 1 < NPG) ? Af[n * NPG + p + 1] : 0.f;
        *(unsigned*)(sm + OFF_ARM + (n * SA + p) * 2) =
            (unsigned)f2bf(v0) | ((unsigned)f2bf(v1) << 16);
    }
    __syncthreads();   // Af reads done before P (overlay) is overwritten

    // ---------------- init Trm P: zero + x ----------------
    for (int i = tid; i < SZ_TRM / 16; i += 256)
        ((f4*)(sm + OFF_P))[i] = (f4){0.f, 0.f, 0.f, 0.f};
    __syncthreads();
    if (tid < NPG) {
        unsigned short h0 = f2bf(x[(nbase + tid) * 3 + 0]);
        unsigned short h1 = f2bf(x[(nbase + tid) * 3 + 1]);
        unsigned short h2 = f2bf(x[(nbase + tid) * 3 + 2]);
        *(unsigned*)(sm + OFF_P + (tid * ST) * 2) = (unsigned)h0 | ((unsigned)h1 << 16);
        *(unsigned short*)(sm + OFF_P + (tid * ST + 2) * 2) = h2;
    }
    __syncthreads();

    // ---------------- 3 ChebConv layers ----------------
    float Tm1[2][16];   // Tx_{s-1} at lane positions
    float Tm2[2][16];   // Tx_{s-2}
    f16v acc[2];
    const float* Ws[3]  = {W1, W2, W3};
    const float* bsv[3] = {b1, b2, b3};

    for (int L = 0; L < 3; L++) {
        const bool l1 = (L == 0);
        const float* Wp = Ws[L];
        acc[0] = zerov16();
        acc[1] = zerov16();

        // Tm1 = Tx0 (layer input) at this lane's positions
        #pragma unroll
        for (int m = 0; m < 2; m++) {
            #pragma unroll
            for (int r = 0; r < 16; r++) {
                int n = (Mt0 + m) * 32 + (r & 3) + 8 * (r >> 2) + 4 * hh;
                Tm1[m][r] = bf2f(*(const unsigned short*)(sm + OFF_P + (n * ST + fo) * 2));
            }
        }

        // O += T @ W[k5] : A = Trm rows b128, B = W global scalars
        auto TW = [&](int offSrc, int k5) {
            const int nKs = l1 ? 1 : 4;
            for (int Ks = 0; Ks < nKs; Ks++) {
                bf8 bw;
                #pragma unroll
                for (int j = 0; j < 8; j++) {
                    int fi = Ks * 16 + 8 * hh + j;
                    float v;
                    if (l1) v = (fi < 3) ? Wp[(k5 * 3 + fi) * HF + fo] : 0.f;
                    else    v = Wp[(k5 * HF + fi) * HF + fo];
                    bw[j] = (short)f2bf(v);
                }
                #pragma unroll
                for (int m = 0; m < 2; m++) {
                    bf8 a = *(const bf8*)(sm + offSrc +
                              (((Mt0 + m) * 32 + l31) * ST + Ks * 16 + 8 * hh) * 2);
                    acc[m] = __builtin_amdgcn_mfma_f32_32x32x16_bf16(a, bw, acc[m], 0, 0, 0);
                }
            }
        };

        // Tx_s = Lhat*Tx_{s-1} (s==1) or 2*Lhat*Tx_{s-1} - Tx_{s-2} (s>=2)
        auto LHAT = [&](int offSrc, int offDst, int s) {
            bf8 bfr[7];   // B frags: Trm^T strided reads (2-way bank aliasing = free)
            #pragma unroll
            for (int Ks = 0; Ks < 7; Ks++) {
                #pragma unroll
                for (int j = 0; j < 8; j++) {
                    int k = Ks * 16 + 8 * hh + j;
                    bfr[Ks][j] = *(const short*)(sm + offSrc + (k * ST + fo) * 2);
                }
            }
            #pragma unroll
            for (int m = 0; m < 2; m++) {
                f16v c = zerov16();
                #pragma unroll
                for (int Ks = 0; Ks < 7; Ks++) {
                    bf8 a = *(const bf8*)(sm + OFF_ARM +
                              (((Mt0 + m) * 32 + l31) * SA + Ks * 16 + 8 * hh) * 2);
                    c = __builtin_amdgcn_mfma_f32_32x32x16_bf16(a, bfr[Ks], c, 0, 0, 0);
                }
                #pragma unroll
                for (int r = 0; r < 16; r++) {
                    float v = (s >= 2) ? (2.f * c[r] - Tm2[m][r]) : c[r];
                    Tm2[m][r] = Tm1[m][r];
                    Tm1[m][r] = v;
                    int n = (Mt0 + m) * 32 + (r & 3) + 8 * (r >> 2) + 4 * hh;
                    *(unsigned short*)(sm + offDst + (n * ST + fo) * 2) = f2bf(v);
                }
            }
        };

        TW(OFF_P, 0);
        LHAT(OFF_P, OFF_Q, 1);  __syncthreads();
        TW(OFF_Q, 1);
        LHAT(OFF_Q, OFF_P, 2);  __syncthreads();
        TW(OFF_P, 2);
        LHAT(OFF_P, OFF_Q, 3);  __syncthreads();
        TW(OFF_Q, 3);
        LHAT(OFF_Q, OFF_P, 4);  __syncthreads();
        TW(OFF_P, 4);
        __syncthreads();        // all TW4 reads of P done before epilogue writes P

        const float bias = bsv[L][fo];
        if (L < 2) {
            #pragma unroll
            for (int m = 0; m < 2; m++) {
                #pragma unroll
                for (int r = 0; r < 16; r++) {
                    float h = fmaxf(acc[m][r] + bias, 0.f);
                    int n = (Mt0 + m) * 32 + (r & 3) + 8 * (r >> 2) + 4 * hh;
                    *(unsigned short*)(sm + OFF_P + (n * ST + fo) * 2) = f2bf(h);
                }
            }
            __syncthreads();
        } else {
            // mean pool (nodes < 100)
            float ssum = 0.f;
            #pragma unroll
            for (int m = 0; m < 2; m++) {
                #pragma unroll
                for (int r = 0; r < 16; r++) {
                    int n = (Mt0 + m) * 32 + (r & 3) + 8 * (r >> 2) + 4 * hh;
                    float h = fmaxf(acc[m][r] + bias, 0.f);
                    if (n < NPG) ssum += h;
                }
            }
            ssum += __shfl_xor(ssum, 32, 64);
            if (hh == 0) atomicAdd(&pool[fo], ssum);
            __syncthreads();
        }
    }

    // ---------------- BN + MLP + log_softmax ----------------
    if (tid < HF) {
        float gv = pool[tid] * (1.0f / NPG);
        gv = (gv - bnm[tid]) * rsqrtf(bnv[tid] + 1e-5f) * bng[tid] + bnb[tid];
        gvn[tid] = gv;
    }
    __syncthreads();
    if (tid < 32) {
        float a = fc1b[tid];
        for (int f = 0; f < HF; f++) a += gvn[f] * fc1w[f * 32 + tid];
        zf[tid] = fmaxf(a, 0.f);
    }
    __syncthreads();
    if (tid < 10) {
        float a = fc2b[tid];
        for (int k = 0; k < 32; k++) a += zf[k] * fc2w[k * 10 + tid];
        logits[tid] = a;
    }
    __syncthreads();
    if (tid == 0) {
        float m = logits[0];
        for (int i = 1; i < 10; i++) m = fmaxf(m, logits[i]);
        float s = 0.f;
        for (int i = 0; i < 10; i++) s += expf(logits[i] - m);
        lsep[0] = m + logf(s);
    }
    __syncthreads();
    if (tid < 10) out[g * 10 + tid] = logits[tid] - lsep[0];
}

extern "C" void kernel_launch(void* const* d_in, const int* in_sizes, int n_in,
                              void* d_out, int out_size, void* d_ws, size_t ws_size,
                              hipStream_t stream) {
    const float* x    = (const float*)d_in[0];
    const int*   ei   = (const int*)d_in[1];
    const float* lmax = (const float*)d_in[3];
    const float* W1   = (const float*)d_in[4];
    const float* b1   = (const float*)d_in[5];
    const float* W2   = (const float*)d_in[6];
    const float* b2   = (const float*)d_in[7];
    const float* W3   = (const float*)d_in[8];
    const float* b3   = (const float*)d_in[9];
    const float* bng  = (const float*)d_in[10];
    const float* bnb  = (const float*)d_in[11];
    const float* bnm  = (const float*)d_in[12];
    const float* bnv  = (const float*)d_in[13];
    const float* fc1w = (const float*)d_in[14];
    const float* fc1b = (const float*)d_in[15];
    const float* fc2w = (const float*)d_in[16];
    const float* fc2b = (const float*)d_in[17];

    const int E = in_sizes[1] / 2;
    const int G = in_sizes[3];
    const int epg = E / G;

    hipFuncSetAttribute((const void*)cheb32,
                        hipFuncAttributeMaxDynamicSharedMemorySize, SMEM_BYTES);

    cheb32<<<G, 256, SMEM_BYTES, stream>>>(x, ei, lmax, W1, b1, W2, b2, W3, b3,
                                           bng, bnb, bnm, bnv, fc1w, fc1b, fc2w, fc2b,
                                           (float*)d_out, E, epg);
}

// Round 4
// 180.819 us; speedup vs baseline: 1.6127x; 1.6127x over previous
//
#include <hip/hip_runtime.h>

#define NPG 100     // nodes per graph
#define HF 64       // hidden width
#define NROW 128    // node rows padded to 4 x 32 tiles
#define SA 120      // Arm row stride (bf16): 112 k-slots + 8 pad
#define ST 72       // Trm row stride (bf16): 64 + 8 pad

typedef float  f4   __attribute__((ext_vector_type(4)));
typedef float  f16v __attribute__((ext_vector_type(16)));
typedef short  bf8  __attribute__((ext_vector_type(8)));

#define SZ_ARM (NROW * SA * 2)        // 30720
#define SZ_TRM (NROW * ST * 2)        // 18432
#define OFF_ARM 0
#define OFF_P   SZ_ARM                // 30720
#define OFF_Q   (OFF_P + SZ_TRM)      // 49152 (ends 67584)
#define OFF_AF  OFF_P                 // fp32 A staging (40000 B overlay, setup only)
#define OFF_MISC 70720
#define SMEM_BYTES (OFF_MISC + 1792)  // 72512 -> 2 blocks/CU

// bf16 weight workspace layout (elements):
//   W1t [5][64][16] @ 0      (fi zero-padded 3->16)
//   W2t [5][64][64] @ 5120
//   W3t [5][64][64] @ 25600   total 46080 elems = 92160 B
#define WT_TOTAL 46080

__device__ __forceinline__ unsigned short f2bf(float f) {
    unsigned u = __float_as_uint(f);
    u += 0x7fffu + ((u >> 16) & 1u);   // round-to-nearest-even
    return (unsigned short)(u >> 16);
}
__device__ __forceinline__ float bf2f(unsigned short h) {
    return __uint_as_float(((unsigned)h) << 16);
}
__device__ __forceinline__ f16v zerov16() {
    f16v z;
    #pragma unroll
    for (int i = 0; i < 16; i++) z[i] = 0.f;
    return z;
}

// One-shot weight transpose+cast: Wt[k5][fo][fi] bf16 into d_ws.
__global__ void wconv(const float* __restrict__ W1, const float* __restrict__ W2,
                      const float* __restrict__ W3, unsigned short* __restrict__ ws)
{
    int idx = blockIdx.x * 256 + threadIdx.x;
    if (idx >= WT_TOTAL) return;
    float v;
    if (idx < 5120) {
        int k5 = idx >> 10, rem = idx & 1023, fo = rem >> 4, fi = rem & 15;
        v = (fi < 3) ? W1[(k5 * 3 + fi) * HF + fo] : 0.f;
    } else if (idx < 25600) {
        int j = idx - 5120;
        int k5 = j >> 12, rem = j & 4095, fo = rem >> 6, fi = rem & 63;
        v = W2[(k5 * HF + fi) * HF + fo];
    } else {
        int j = idx - 25600;
        int k5 = j >> 12, rem = j & 4095, fo = rem >> 6, fi = rem & 63;
        v = W3[(k5 * HF + fi) * HF + fo];
    }
    ws[idx] = f2bf(v);
}

// One block per graph, 256 threads = 4 waves, 2 blocks/CU.
// All matmuls on mfma_f32_32x32x16_bf16.
//   LHAT: D[n][f] = sum_k Arm[n][k] * T[k][f]   (A=Arm b128, B=T strided b16)
//   TW:   O[n][fo] += sum_fi T[n][fi] * Wt[fo][fi] (A=T b128, B=Wt b128 from d_ws)
// C/D: col = lane&31, row = (reg&3)+8*(reg>>2)+4*(lane>>5)
// Chebyshev old term read back bf16 from the dst ping-pong buffer (no reg state).
__launch_bounds__(256, 2)
__global__ void cheb32(const float* __restrict__ x, const int* __restrict__ ei,
                       const float* __restrict__ lambda_max,
                       const unsigned short* __restrict__ Wt,
                       const float* __restrict__ b1, const float* __restrict__ b2,
                       const float* __restrict__ b3,
                       const float* __restrict__ bng, const float* __restrict__ bnb,
                       const float* __restrict__ bnm, const float* __restrict__ bnv,
                       const float* __restrict__ fc1w, const float* __restrict__ fc1b,
                       const float* __restrict__ fc2w, const float* __restrict__ fc2b,
                       float* __restrict__ out, int E_total, int epg)
{
    extern __shared__ char sm[];
    const int tid = threadIdx.x;
    const int g = blockIdx.x;
    const int ebase = g * epg, nbase = g * NPG;
    const int wg = tid >> 6, lane = tid & 63;
    const int l31 = lane & 31, hh = lane >> 5;
    const int Ntf = wg & 1;
    const int Mt0 = (wg >> 1) * 2;
    const int fo = Ntf * 32 + l31;

    float* Af     = (float*)(sm + OFF_AF);
    int*   deg    = (int*)(sm + OFF_MISC);
    float* dis    = (float*)(sm + OFF_MISC + 512);
    float* pool   = (float*)(sm + OFF_MISC + 1024);
    float* gvn    = (float*)(sm + OFF_MISC + 1280);
    float* zf     = (float*)(sm + OFF_MISC + 1536);
    float* logits = (float*)(sm + OFF_MISC + 1664);
    float* lsep   = (float*)(sm + OFF_MISC + 1728);

    const float lam = lambda_max[g];
    const float two_l = 2.0f / lam;
    const float cl = two_l - 1.0f;

    // ---------------- build dense Lhat (fp32 staging -> bf16 Arm) ----------------
    for (int i = tid; i < 2500; i += 256) ((f4*)Af)[i] = (f4){0.f, 0.f, 0.f, 0.f};
    if (tid < NPG) deg[tid] = 0;
    if (tid < HF) pool[tid] = 0.f;
    __syncthreads();
    for (int e = tid; e < epg; e += 256)
        atomicAdd(&deg[ei[ebase + e] - nbase], 1);
    __syncthreads();
    if (tid < NPG) dis[tid] = deg[tid] > 0 ? rsqrtf((float)deg[tid]) : 0.f;
    __syncthreads();
    for (int e = tid; e < epg; e += 256) {
        int r = ei[ebase + e] - nbase;
        int c = ei[E_total + ebase + e] - nbase;
        atomicAdd(&Af[r * NPG + c], -two_l * dis[r] * dis[c]);
    }
    __syncthreads();
    if (tid < NPG) Af[tid * NPG + tid] += cl;
    __syncthreads();
    for (int u = tid; u < NROW * 56; u += 256) {
        int n = u / 56, p = (u % 56) * 2;
        float v0 = (n < NPG && p     < NPG) ? Af[n * NPG + p]     : 0.f;
        float v1 = (n < NPG && p + 1 < NPG) ? Af[n * NPG + p + 1] : 0.f;
        *(unsigned*)(sm + OFF_ARM + (n * SA + p) * 2) =
            (unsigned)f2bf(v0) | ((unsigned)f2bf(v1) << 16);
    }
    __syncthreads();   // Af reads done before P (overlay) is overwritten

    // ---------------- init Trm P: zero + x ----------------
    for (int i = tid; i < SZ_TRM / 16; i += 256)
        ((f4*)(sm + OFF_P))[i] = (f4){0.f, 0.f, 0.f, 0.f};
    __syncthreads();
    if (tid < NPG) {
        unsigned short h0 = f2bf(x[(nbase + tid) * 3 + 0]);
        unsigned short h1 = f2bf(x[(nbase + tid) * 3 + 1]);
        unsigned short h2 = f2bf(x[(nbase + tid) * 3 + 2]);
        *(unsigned*)(sm + OFF_P + (tid * ST) * 2) = (unsigned)h0 | ((unsigned)h1 << 16);
        *(unsigned short*)(sm + OFF_P + (tid * ST + 2) * 2) = h2;
    }
    __syncthreads();

    // ---------------- 3 ChebConv layers ----------------
    f16v acc[2];
    const float* bsv[3] = {b1, b2, b3};

    for (int L = 0; L < 3; L++) {
        const bool l1 = (L == 0);
        const unsigned short* Wl = l1 ? Wt : (Wt + (L == 1 ? 5120 : 25600));
        acc[0] = zerov16();
        acc[1] = zerov16();

        // O += T @ W[k5] : A = Trm rows b128, B = Wt b128 (L1/L2-hot)
        auto TW = [&](int offSrc, int k5) {
            const int nKs = l1 ? 1 : 4;
            for (int Ks = 0; Ks < nKs; Ks++) {
                bf8 bw;
                if (l1) bw = *(const bf8*)(Wl + (k5 * 64 + fo) * 16 + 8 * hh);
                else    bw = *(const bf8*)(Wl + (k5 * 64 + fo) * 64 + Ks * 16 + 8 * hh);
                #pragma unroll
                for (int m = 0; m < 2; m++) {
                    bf8 a = *(const bf8*)(sm + offSrc +
                              (((Mt0 + m) * 32 + l31) * ST + Ks * 16 + 8 * hh) * 2);
                    acc[m] = __builtin_amdgcn_mfma_f32_32x32x16_bf16(a, bw, acc[m], 0, 0, 0);
                }
            }
        };

        // Tx_s = Lhat*Tx_{s-1} (s==1) or 2*Lhat*Tx_{s-1} - Tx_{s-2} (s>=2)
        // old Tx_{s-2} read bf16 from dst buffer before overwrite (single-owner lanes)
        auto LHAT = [&](int offSrc, int offDst, int s) {
            bf8 bfr[7];
            #pragma unroll
            for (int Ks = 0; Ks < 7; Ks++) {
                #pragma unroll
                for (int j = 0; j < 8; j++) {
                    int k = Ks * 16 + 8 * hh + j;
                    bfr[Ks][j] = *(const short*)(sm + offSrc + (k * ST + fo) * 2);
                }
            }
            #pragma unroll
            for (int m = 0; m < 2; m++) {
                f16v c = zerov16();
                #pragma unroll
                for (int Ks = 0; Ks < 7; Ks++) {
                    bf8 a = *(const bf8*)(sm + OFF_ARM +
                              (((Mt0 + m) * 32 + l31) * SA + Ks * 16 + 8 * hh) * 2);
                    c = __builtin_amdgcn_mfma_f32_32x32x16_bf16(a, bfr[Ks], c, 0, 0, 0);
                }
                #pragma unroll
                for (int r = 0; r < 16; r++) {
                    int n = (Mt0 + m) * 32 + (r & 3) + 8 * (r >> 2) + 4 * hh;
                    char* p = sm + offDst + (n * ST + fo) * 2;
                    float v = c[r];
                    if (s >= 2) v = 2.f * v - bf2f(*(const unsigned short*)p);
                    *(unsigned short*)p = f2bf(v);
                }
            }
        };

        TW(OFF_P, 0);
        LHAT(OFF_P, OFF_Q, 1);  __syncthreads();
        TW(OFF_Q, 1);
        LHAT(OFF_Q, OFF_P, 2);  __syncthreads();
        TW(OFF_P, 2);
        LHAT(OFF_P, OFF_Q, 3);  __syncthreads();
        TW(OFF_Q, 3);
        LHAT(OFF_Q, OFF_P, 4);  __syncthreads();
        TW(OFF_P, 4);
        __syncthreads();        // all TW4 reads of P done before epilogue writes P

        const float bias = bsv[L][fo];
        if (L < 2) {
            #pragma unroll
            for (int m = 0; m < 2; m++) {
                #pragma unroll
                for (int r = 0; r < 16; r++) {
                    float h = fmaxf(acc[m][r] + bias, 0.f);
                    int n = (Mt0 + m) * 32 + (r & 3) + 8 * (r >> 2) + 4 * hh;
                    *(unsigned short*)(sm + OFF_P + (n * ST + fo) * 2) = f2bf(h);
                }
            }
            __syncthreads();
        } else {
            float ssum = 0.f;
            #pragma unroll
            for (int m = 0; m < 2; m++) {
                #pragma unroll
                for (int r = 0; r < 16; r++) {
                    int n = (Mt0 + m) * 32 + (r & 3) + 8 * (r >> 2) + 4 * hh;
                    float h = fmaxf(acc[m][r] + bias, 0.f);
                    if (n < NPG) ssum += h;
                }
            }
            ssum += __shfl_xor(ssum, 32, 64);
            if (hh == 0) atomicAdd(&pool[fo], ssum);
            __syncthreads();
        }
    }

    // ---------------- BN + MLP + log_softmax ----------------
    if (tid < HF) {
        float gv = pool[tid] * (1.0f / NPG);
        gv = (gv - bnm[tid]) * rsqrtf(bnv[tid] + 1e-5f) * bng[tid] + bnb[tid];
        gvn[tid] = gv;
    }
    __syncthreads();
    if (tid < 32) {
        float a = fc1b[tid];
        for (int f = 0; f < HF; f++) a += gvn[f] * fc1w[f * 32 + tid];
        zf[tid] = fmaxf(a, 0.f);
    }
    __syncthreads();
    if (tid < 10) {
        float a = fc2b[tid];
        for (int k = 0; k < 32; k++) a += zf[k] * fc2w[k * 10 + tid];
        logits[tid] = a;
    }
    __syncthreads();
    if (tid == 0) {
        float m = logits[0];
        for (int i = 1; i < 10; i++) m = fmaxf(m, logits[i]);
        float s = 0.f;
        for (int i = 0; i < 10; i++) s += expf(logits[i] - m);
        lsep[0] = m + logf(s);
    }
    __syncthreads();
    if (tid < 10) out[g * 10 + tid] = logits[tid] - lsep[0];
}

extern "C" void kernel_launch(void* const* d_in, const int* in_sizes, int n_in,
                              void* d_out, int out_size, void* d_ws, size_t ws_size,
                              hipStream_t stream) {
    const float* x    = (const float*)d_in[0];
    const int*   ei   = (const int*)d_in[1];
    const float* lmax = (const float*)d_in[3];
    const float* W1   = (const float*)d_in[4];
    const float* b1   = (const float*)d_in[5];
    const float* W2   = (const float*)d_in[6];
    const float* b2   = (const float*)d_in[7];
    const float* W3   = (const float*)d_in[8];
    const float* b3   = (const float*)d_in[9];
    const float* bng  = (const float*)d_in[10];
    const float* bnb  = (const float*)d_in[11];
    const float* bnm  = (const float*)d_in[12];
    const float* bnv  = (const float*)d_in[13];
    const float* fc1w = (const float*)d_in[14];
    const float* fc1b = (const float*)d_in[15];
    const float* fc2w = (const float*)d_in[16];
    const float* fc2b = (const float*)d_in[17];

    const int E = in_sizes[1] / 2;
    const int G = in_sizes[3];
    const int epg = E / G;

    unsigned short* Wt = (unsigned short*)d_ws;

    wconv<<<(WT_TOTAL + 255) / 256, 256, 0, stream>>>(W1, W2, W3, Wt);

    hipFuncSetAttribute((const void*)cheb32,
                        hipFuncAttributeMaxDynamicSharedMemorySize, SMEM_BYTES);

    cheb32<<<G, 256, SMEM_BYTES, stream>>>(x, ei, lmax, Wt, b1, b2, b3,
                                           bng, bnb, bnm, bnv, fc1w, fc1b, fc2w, fc2b,
                                           (float*)d_out, E, epg);
}